// Round 1
// baseline (343.078 us; speedup 1.0000x reference)
//
#include <hip/hip_runtime.h>

typedef float f32x4 __attribute__((ext_vector_type(4)));
typedef float fvec4 __attribute__((ext_vector_type(4)));
typedef __bf16 bf16x8 __attribute__((ext_vector_type(8)));
typedef unsigned short u16;
typedef u16 u16x8 __attribute__((ext_vector_type(8)));
typedef u16 u16x4 __attribute__((ext_vector_type(4)));

#define SCALE_Q 0.18257418583505536f  /* 30^-0.5 */

__device__ __forceinline__ u16 f2bf(float f) {
    union { __bf16 h; u16 u; } cv; cv.h = (__bf16)f; return cv.u;
}
__device__ __forceinline__ float bf2f(u16 u) {
    union { __bf16 h; u16 u; } cv; cv.u = u; return (float)cv.h;
}

// ---------------------------------------------------------------------------
// prep: weight transposes (bf16, [col][k] padded), bias table, pad zeroing
// segments: qkvT 110592 | projT 36864 | fc1T 73728 | fc2T 73728 |
//           bias_t 884736 | k_s pads 393216 | attn_out pads 393216  = 1966080
// ---------------------------------------------------------------------------
__global__ __launch_bounds__(256)
void prep_k(const float* __restrict__ qkv_w, const float* __restrict__ proj_w,
            const float* __restrict__ fc1_w, const float* __restrict__ fc2_w,
            const int* __restrict__ rpi, const float* __restrict__ rpb,
            u16* __restrict__ qkvT, u16* __restrict__ projT,
            u16* __restrict__ fc1T, u16* __restrict__ fc2T,
            u16* __restrict__ bias_t, unsigned* __restrict__ ks_u32,
            unsigned* __restrict__ ao_u32)
{
    int idx = blockIdx.x * 256 + threadIdx.x;
    if (idx < 110592) {                       // qkvT[576][192]
        int col = idx / 192, k = idx % 192;
        qkvT[idx] = (col < 540 && k < 180) ? f2bf(qkv_w[k * 540 + col]) : (u16)0;
    } else if (idx < 147456) {                // projT[192][192]
        int i = idx - 110592; int col = i / 192, k = i % 192;
        projT[i] = (col < 180 && k < 180) ? f2bf(proj_w[k * 180 + col]) : (u16)0;
    } else if (idx < 221184) {                // fc1T[384][192]
        int i = idx - 147456; int col = i / 192, k = i % 192;
        fc1T[i] = (col < 360 && k < 180) ? f2bf(fc1_w[k * 360 + col]) : (u16)0;
    } else if (idx < 294912) {                // fc2T[192][384]
        int i = idx - 221184; int col = i / 384, k = i % 384;
        fc2T[i] = (col < 180 && k < 360) ? f2bf(fc2_w[k * 180 + col]) : (u16)0;
    } else if (idx < 1179648) {               // bias_t[6][576][256]
        int i = idx - 294912;
        int hh = i / 147456; int rem = i % 147456;
        int n = rem >> 8, q = rem & 255;
        bias_t[i] = f2bf(rpb[rpi[q * 576 + n] * 6 + hh]);
    } else if (idx < 1572864) {               // zero k_s dims 30,31 per (t,h)
        int i = idx - 1179648;
        ks_u32[i * 16 + 15] = 0u;
    } else if (idx < 1966080) {               // zero attn_out cols 180..191
        int i = idx - 1572864;
        int t = i / 6, j = i % 6;
        ao_u32[t * 96 + 90 + j] = 0u;
    }
}

// ---------------------------------------------------------------------------
// LayerNorm: wave per row (180 f32 = 45 float4), writes bf16 [row][192] (pad 0)
// ---------------------------------------------------------------------------
__global__ __launch_bounds__(256)
void ln_k(const float* __restrict__ in, const float* __restrict__ w,
          const float* __restrict__ b, u16* __restrict__ out)
{
    int row = blockIdx.x * 4 + (threadIdx.x >> 6);
    int lane = threadIdx.x & 63;
    fvec4 v = {0.f, 0.f, 0.f, 0.f};
    if (lane < 45) v = *(const fvec4*)(in + (long)row * 180 + lane * 4);
    float s  = v.x + v.y + v.z + v.w;
    float sq = v.x * v.x + v.y * v.y + v.z * v.z + v.w * v.w;
    for (int m = 1; m < 64; m <<= 1) { s += __shfl_xor(s, m); sq += __shfl_xor(sq, m); }
    float mean = s * (1.f / 180.f);
    float var  = sq * (1.f / 180.f) - mean * mean;
    float rstd = rsqrtf(var + 1e-5f);
    if (lane < 45) {
        u16x4 o;
        #pragma unroll
        for (int j = 0; j < 4; j++) {
            int c = lane * 4 + j;
            o[j] = f2bf((v[j] - mean) * rstd * w[c] + b[c]);
        }
        *(u16x4*)(out + (long)row * 192 + lane * 4) = o;
    } else if (lane < 48) {
        u16x4 z = {0, 0, 0, 0};
        *(u16x4*)(out + (long)row * 192 + 180 + (lane - 45) * 4) = z;
    }
}

// ---------------------------------------------------------------------------
// GEMM: C[M][N] = A[M][K]bf16 @ Bt[N][K]bf16, 128x64 block tile, 4 waves 2x2,
// 16x16x32 MFMA, f32 accum. EPI: 0=qkv scatter, 1=proj(+bias+resid f32),
// 2=fc1 (gelu->bf16), 3=fc2 (+bias+resid f32)
// ---------------------------------------------------------------------------
template<int KTOT, int EPI>
__global__ __launch_bounds__(256)
void gemm_k(const u16* __restrict__ A, const u16* __restrict__ Bt,
            const float* __restrict__ bias, const float* __restrict__ resid,
            void* __restrict__ o0, void* __restrict__ o1, void* __restrict__ o2)
{
    __shared__ u16 lds_a[128 * 32];
    __shared__ u16 lds_b[64 * 32];
    const int tid = threadIdx.x;
    const int l = tid & 63, wv = tid >> 6;
    const int wm = wv >> 1, wn = wv & 1;
    const int l15 = l & 15, lg = l >> 4;
    const long rowb = (long)blockIdx.x * 128;
    const int colb = blockIdx.y * 64;
    const f32x4 fz = {0.f, 0.f, 0.f, 0.f};

    f32x4 acc[4][2];
    #pragma unroll
    for (int i = 0; i < 4; i++) { acc[i][0] = fz; acc[i][1] = fz; }

    const int r = tid >> 2, g = tid & 3;
    for (int kk = 0; kk < KTOT; kk += 32) {
        u16x8 va0 = *(const u16x8*)(A + (rowb + r) * KTOT + kk + g * 8);
        u16x8 va1 = *(const u16x8*)(A + (rowb + 64 + r) * KTOT + kk + g * 8);
        u16x8 vb  = *(const u16x8*)(Bt + (long)(colb + r) * KTOT + kk + g * 8);
        *(u16x8*)(lds_a + r * 32 + g * 8) = va0;
        *(u16x8*)(lds_a + (64 + r) * 32 + g * 8) = va1;
        *(u16x8*)(lds_b + r * 32 + g * 8) = vb;
        __syncthreads();
        bf16x8 af[4], bfr[2];
        #pragma unroll
        for (int mi = 0; mi < 4; mi++)
            af[mi] = *(const bf16x8*)(lds_a + (wm * 64 + mi * 16 + l15) * 32 + lg * 8);
        #pragma unroll
        for (int nd = 0; nd < 2; nd++)
            bfr[nd] = *(const bf16x8*)(lds_b + (wn * 32 + nd * 16 + l15) * 32 + lg * 8);
        #pragma unroll
        for (int mi = 0; mi < 4; mi++)
            #pragma unroll
            for (int nd = 0; nd < 2; nd++)
                acc[mi][nd] = __builtin_amdgcn_mfma_f32_16x16x32_bf16(af[mi], bfr[nd], acc[mi][nd], 0, 0, 0);
        __syncthreads();
    }

    #pragma unroll
    for (int mi = 0; mi < 4; mi++) {
        #pragma unroll
        for (int nd = 0; nd < 2; nd++) {
            #pragma unroll
            for (int rr = 0; rr < 4; rr++) {
                long t = rowb + wm * 64 + mi * 16 + lg * 4 + rr;
                int c = colb + wn * 32 + nd * 16 + l15;
                float v = acc[mi][nd][rr];
                if (EPI == 0) {
                    if (c < 540) {
                        v += bias[c];
                        int y = (int)(t >> 8), x = (int)(t & 255);
                        if (c < 180) {
                            int hh = c / 30, d = c % 30;
                            int win = ((y >> 4) << 4) | (x >> 4);
                            int qrow = ((y & 15) << 4) | (x & 15);
                            ((u16*)o0)[(((long)(win * 6 + hh)) * 256 + qrow) * 32 + d] = f2bf(v * SCALE_Q);
                        } else if (c < 360) {
                            int c2 = c - 180; int hh = c2 / 30, d = c2 % 30;
                            ((u16*)o1)[(t * 6 + hh) * 32 + d] = f2bf(v);
                        } else {
                            int c2 = c - 360; int hh = c2 / 30, d = c2 % 30;
                            ((u16*)o2)[(t * 6 + hh) * 32 + d] = f2bf(v);
                        }
                    }
                } else if (EPI == 1) {
                    if (c < 180) ((float*)o0)[t * 180 + c] = v + bias[c] + resid[t * 180 + c];
                } else if (EPI == 2) {
                    float bb = (c < 360) ? bias[c] : 0.f;
                    float xx = v + bb;
                    float ge = 0.5f * xx * (1.f + erff(xx * 0.70710678118f));
                    ((u16*)o0)[t * 384 + c] = f2bf(ge);
                } else {
                    if (c < 180) ((float*)o0)[t * 180 + c] = v + bias[c] + resid[t * 180 + c];
                }
            }
        }
    }
}

// ---------------------------------------------------------------------------
// Attention: block=(window,head), 4 waves x 64 q-rows, flash over 9 chunks of
// 64 keys. Swapped QK^T (S^T = K@Q^T) -> softmax state is q=lane&15-local.
// PV as V^T @ P^T keeps accumulator in same q-layout.
// ---------------------------------------------------------------------------
__global__ __launch_bounds__(256)
void attn_k(const u16* __restrict__ q_g, const u16* __restrict__ k_s,
            const u16* __restrict__ v_s, const u16* __restrict__ bias_t,
            u16* __restrict__ attn_out)
{
    __shared__ u16 kc[64 * 32];        // [key][dim32]
    __shared__ u16 vT[32 * 72];        // [dim][key64 pad72]
    __shared__ u16 p_lds[4][64 * 72];  // per wave: [q64][key64 pad72]

    const int w = blockIdx.x, h = blockIdx.y;
    const int wy = w >> 4, wx = w & 15;
    const int tid = threadIdx.x;
    const int wv = tid >> 6, l = tid & 63;
    const int l15 = l & 15, lg = l >> 4;
    const f32x4 fz = {0.f, 0.f, 0.f, 0.f};

    // Q B-fragments (col=q=l15, k=dims lg*8..+8); q pre-scaled by SCALE
    bf16x8 qb[4];
    #pragma unroll
    for (int ni = 0; ni < 4; ni++) {
        int qrow = wv * 64 + ni * 16 + l15;
        qb[ni] = *(const bf16x8*)(q_g + (((long)(w * 6 + h)) * 256 + qrow) * 32 + lg * 8);
    }

    f32x4 acc[2][4];   // [dim-frag][q-frag]
    #pragma unroll
    for (int i = 0; i < 2; i++)
        #pragma unroll
        for (int j = 0; j < 4; j++) acc[i][j] = fz;
    float mrow[4] = {-1e30f, -1e30f, -1e30f, -1e30f};
    float lrow[4] = {0.f, 0.f, 0.f, 0.f};

    const int skey = tid >> 2, sg = tid & 3;   // kc staging
    const int sd = tid & 31, skb = tid >> 5;   // vT staging

    for (int ch = 0; ch < 9; ++ch) {
        {   // stage K chunk [64][32]; OOB keys -> 0 (matches jnp.pad)
            int n = ch * 64 + skey;
            int oy = n / 24, ox = n - oy * 24;
            int y = wy * 16 - 4 + oy, x = wx * 16 - 4 + ox;
            u16x8 kval = {0, 0, 0, 0, 0, 0, 0, 0};
            if (y >= 0 && y < 256 && x >= 0 && x < 256)
                kval = *(const u16x8*)(k_s + (((long)(y * 256 + x)) * 6 + h) * 32 + sg * 8);
            *(u16x8*)(kc + skey * 32 + sg * 8) = kval;
        }
        {   // stage V chunk transposed [32][64]
            u16x8 pv;
            #pragma unroll
            for (int j = 0; j < 8; j++) {
                int n = ch * 64 + skb * 8 + j;
                int oy = n / 24, ox = n - oy * 24;
                int y = wy * 16 - 4 + oy, x = wx * 16 - 4 + ox;
                pv[j] = (y >= 0 && y < 256 && x >= 0 && x < 256)
                      ? v_s[(((long)(y * 256 + x)) * 6 + h) * 32 + sd] : (u16)0;
            }
            *(u16x8*)(vT + sd * 72 + skb * 8) = pv;
        }
        __syncthreads();

        // S^T[key][q] = K @ Q^T
        bf16x8 ka[4];
        #pragma unroll
        for (int mi = 0; mi < 4; mi++)
            ka[mi] = *(const bf16x8*)(kc + (mi * 16 + l15) * 32 + lg * 8);
        f32x4 s[4][4];
        #pragma unroll
        for (int mi = 0; mi < 4; mi++)
            #pragma unroll
            for (int ni = 0; ni < 4; ni++)
                s[mi][ni] = __builtin_amdgcn_mfma_f32_16x16x32_bf16(ka[mi], qb[ni], fz, 0, 0, 0);

        // + bias, per-q chunk max
        float mx[4] = {-1e30f, -1e30f, -1e30f, -1e30f};
        #pragma unroll
        for (int mi = 0; mi < 4; mi++) {
            #pragma unroll
            for (int rr = 0; rr < 4; rr++) {
                int keyg = ch * 64 + mi * 16 + lg * 4 + rr;
                long bb = ((long)h * 576 + keyg) * 256 + wv * 64 + l15;
                #pragma unroll
                for (int ni = 0; ni < 4; ni++) {
                    s[mi][ni][rr] += bf2f(bias_t[bb + ni * 16]);
                    mx[ni] = fmaxf(mx[ni], s[mi][ni][rr]);
                }
            }
        }
        #pragma unroll
        for (int ni = 0; ni < 4; ni++) {
            mx[ni] = fmaxf(mx[ni], __shfl_xor(mx[ni], 16));
            mx[ni] = fmaxf(mx[ni], __shfl_xor(mx[ni], 32));
        }
        float f[4], sm[4];
        #pragma unroll
        for (int ni = 0; ni < 4; ni++) {
            float mn = fmaxf(mrow[ni], mx[ni]);
            f[ni] = __expf(mrow[ni] - mn);
            mrow[ni] = mn;
            sm[ni] = 0.f;
        }
        // P = exp(S - m), write P^T-redistribution buffer
        #pragma unroll
        for (int mi = 0; mi < 4; mi++)
            #pragma unroll
            for (int ni = 0; ni < 4; ni++)
                #pragma unroll
                for (int rr = 0; rr < 4; rr++) {
                    float p = __expf(s[mi][ni][rr] - mrow[ni]);
                    sm[ni] += p;
                    p_lds[wv][(ni * 16 + l15) * 72 + mi * 16 + lg * 4 + rr] = f2bf(p);
                }
        #pragma unroll
        for (int ni = 0; ni < 4; ni++) {
            sm[ni] += __shfl_xor(sm[ni], 16);
            sm[ni] += __shfl_xor(sm[ni], 32);
            lrow[ni] = lrow[ni] * f[ni] + sm[ni];
        }
        #pragma unroll
        for (int mi2 = 0; mi2 < 2; mi2++)
            #pragma unroll
            for (int ni = 0; ni < 4; ni++)
                #pragma unroll
                for (int rr = 0; rr < 4; rr++)
                    acc[mi2][ni][rr] *= f[ni];

        // O^T += V^T @ P^T  (A=vT rows=dims, B=p_lds cols=q)
        #pragma unroll
        for (int ks = 0; ks < 2; ks++) {
            bf16x8 va[2];
            #pragma unroll
            for (int mi2 = 0; mi2 < 2; mi2++)
                va[mi2] = *(const bf16x8*)(vT + (mi2 * 16 + l15) * 72 + ks * 32 + lg * 8);
            #pragma unroll
            for (int ni = 0; ni < 4; ni++) {
                bf16x8 pb = *(const bf16x8*)(p_lds[wv] + (ni * 16 + l15) * 72 + ks * 32 + lg * 8);
                #pragma unroll
                for (int mi2 = 0; mi2 < 2; mi2++)
                    acc[mi2][ni] = __builtin_amdgcn_mfma_f32_16x16x32_bf16(va[mi2], pb, acc[mi2][ni], 0, 0, 0);
            }
        }
        __syncthreads();
    }

    // epilogue: O[q][dim]/l -> attn_out[token][h*30+dim] bf16
    #pragma unroll
    for (int ni = 0; ni < 4; ni++) {
        float inv = 1.f / lrow[ni];
        int q = wv * 64 + ni * 16 + l15;
        int y = wy * 16 + (q >> 4), x = wx * 16 + (q & 15);
        long base = ((long)(y * 256 + x)) * 192 + h * 30;
        #pragma unroll
        for (int mi2 = 0; mi2 < 2; mi2++)
            #pragma unroll
            for (int rr = 0; rr < 4; rr++) {
                int dim = mi2 * 16 + lg * 4 + rr;
                if (dim < 30)
                    attn_out[base + dim] = f2bf(acc[mi2][ni][rr] * inv);
            }
    }
}

// ---------------------------------------------------------------------------
extern "C" void kernel_launch(void* const* d_in, const int* in_sizes, int n_in,
                              void* d_out, int out_size, void* d_ws, size_t ws_size,
                              hipStream_t stream)
{
    (void)in_sizes; (void)n_in; (void)out_size; (void)ws_size;
    const float* x      = (const float*)d_in[0];
    const int*   rpi    = (const int*)d_in[1];
    const float* n1w    = (const float*)d_in[2];
    const float* n1b    = (const float*)d_in[3];
    const float* qkv_w  = (const float*)d_in[4];
    const float* qkv_b  = (const float*)d_in[5];
    const float* rpb    = (const float*)d_in[6];
    const float* proj_w = (const float*)d_in[7];
    const float* proj_b = (const float*)d_in[8];
    const float* n2w    = (const float*)d_in[9];
    const float* n2b    = (const float*)d_in[10];
    const float* fc1_w  = (const float*)d_in[11];
    const float* fc1_b  = (const float*)d_in[12];
    const float* fc2_w  = (const float*)d_in[13];
    const float* fc2_b  = (const float*)d_in[14];
    float* out = (float*)d_out;

    char* ws = (char*)d_ws;
    size_t off = 0;
    auto alloc = [&](size_t bytes) -> void* {
        void* p = ws + off; off += (bytes + 511) & ~(size_t)511; return p;
    };
    u16*   xn     = (u16*)alloc(65536ull * 192 * 2);  // ln1 out, reused for ln2 out
    u16*   q_g    = (u16*)alloc(65536ull * 192 * 2);  // [win][h][qrow][32]
    u16*   k_s    = (u16*)alloc(65536ull * 192 * 2);  // [y][x][h][32]
    u16*   v_s    = (u16*)alloc(65536ull * 192 * 2);
    u16*   ao     = (u16*)alloc(65536ull * 192 * 2);  // attn out bf16 [t][192]
    float* x2     = (float*)alloc(65536ull * 180 * 4);
    u16*   bias_t = (u16*)alloc(6ull * 576 * 256 * 2);
    u16*   qkvT   = (u16*)alloc(576ull * 192 * 2);
    u16*   projT  = (u16*)alloc(192ull * 192 * 2);
    u16*   fc1T   = (u16*)alloc(384ull * 192 * 2);
    u16*   fc2T   = (u16*)alloc(192ull * 384 * 2);
    u16*   h1     = q_g;  // q_g+k_s are adjacent 2*25165824 = 65536*384*2 bytes

    prep_k<<<dim3(7680), dim3(256), 0, stream>>>(qkv_w, proj_w, fc1_w, fc2_w,
        rpi, rpb, qkvT, projT, fc1T, fc2T, bias_t, (unsigned*)k_s, (unsigned*)ao);
    ln_k<<<dim3(16384), dim3(256), 0, stream>>>(x, n1w, n1b, xn);
    gemm_k<192, 0><<<dim3(512, 9), dim3(256), 0, stream>>>(
        xn, qkvT, qkv_b, (const float*)nullptr, q_g, k_s, v_s);
    attn_k<<<dim3(256, 6), dim3(256), 0, stream>>>(q_g, k_s, v_s, bias_t, ao);
    gemm_k<192, 1><<<dim3(512, 3), dim3(256), 0, stream>>>(
        ao, projT, proj_b, x, x2, nullptr, nullptr);
    ln_k<<<dim3(16384), dim3(256), 0, stream>>>(x2, n2w, n2b, xn);
    gemm_k<192, 2><<<dim3(512, 6), dim3(256), 0, stream>>>(
        xn, fc1T, fc1_b, (const float*)nullptr, h1, nullptr, nullptr);
    gemm_k<384, 3><<<dim3(512, 3), dim3(256), 0, stream>>>(
        h1, fc2T, fc2_b, x2, out, nullptr, nullptr);
}

// Round 2
// 298.550 us; speedup vs baseline: 1.1491x; 1.1491x over previous
//
#include <hip/hip_runtime.h>

typedef float f32x4 __attribute__((ext_vector_type(4)));
typedef float fvec4 __attribute__((ext_vector_type(4)));
typedef __bf16 bf16x8 __attribute__((ext_vector_type(8)));
typedef unsigned short u16;
typedef u16 u16x8 __attribute__((ext_vector_type(8)));
typedef u16 u16x4 __attribute__((ext_vector_type(4)));

#define SCALE_Q 0.18257418583505536f  /* 30^-0.5 */

__device__ __forceinline__ u16 f2bf(float f) {
    union { __bf16 h; u16 u; } cv; cv.h = (__bf16)f; return cv.u;
}
__device__ __forceinline__ float bf2f(u16 u) {
    union { __bf16 h; u16 u; } cv; cv.u = u; return (float)cv.h;
}

// async global->LDS, 16B per lane; LDS dest = wave-uniform base + lane*16
#define GLD16(gsrc, ldst) __builtin_amdgcn_global_load_lds( \
    (const __attribute__((address_space(1))) unsigned*)(gsrc), \
    (__attribute__((address_space(3))) unsigned*)(ldst), 16, 0, 0)

// ---------------------------------------------------------------------------
// prep: weight transposes (bf16, [col][k] padded), bias table, pad zeroing
// ---------------------------------------------------------------------------
__global__ __launch_bounds__(256)
void prep_k(const float* __restrict__ qkv_w, const float* __restrict__ proj_w,
            const float* __restrict__ fc1_w, const float* __restrict__ fc2_w,
            const int* __restrict__ rpi, const float* __restrict__ rpb,
            u16* __restrict__ qkvT, u16* __restrict__ projT,
            u16* __restrict__ fc1T, u16* __restrict__ fc2T,
            u16* __restrict__ bias2, unsigned* __restrict__ ks_u32,
            unsigned* __restrict__ ao_u32, u16* __restrict__ zbuf)
{
    int idx = blockIdx.x * 256 + threadIdx.x;
    if (idx < 110592) {                       // qkvT[576][192]
        int col = idx / 192, k = idx % 192;
        qkvT[idx] = (col < 540 && k < 180) ? f2bf(qkv_w[k * 540 + col]) : (u16)0;
    } else if (idx < 147456) {                // projT[192][192]
        int i = idx - 110592; int col = i / 192, k = i % 192;
        projT[i] = (col < 180 && k < 180) ? f2bf(proj_w[k * 180 + col]) : (u16)0;
    } else if (idx < 221184) {                // fc1T[384][192]
        int i = idx - 147456; int col = i / 192, k = i % 192;
        fc1T[i] = (col < 360 && k < 180) ? f2bf(fc1_w[k * 360 + col]) : (u16)0;
    } else if (idx < 294912) {                // fc2T[192][384]
        int i = idx - 221184; int col = i / 384, k = i % 384;
        fc2T[i] = (col < 180 && k < 360) ? f2bf(fc2_w[k * 180 + col]) : (u16)0;
    } else if (idx < 1179648) {               // bias2[6][144 keygrp][256 q][4]
        int i = idx - 294912;
        int hh = i / 147456, rem = i % 147456;
        int kg4 = rem >> 10, q = (rem >> 2) & 255, rr = rem & 3;
        int n = kg4 * 4 + rr;
        bias2[i] = f2bf(rpb[rpi[q * 576 + n] * 6 + hh]);
    } else if (idx < 1572864) {               // zero k_s dims 30,31 per (t,h)
        int i = idx - 1179648;
        ks_u32[i * 16 + 15] = 0u;
    } else if (idx < 1966080) {               // zero attn_out cols 180..191
        int i = idx - 1572864;
        int t = i / 6, j = i % 6;
        ao_u32[t * 96 + 90 + j] = 0u;
    } else if (idx < 1966208) {               // zero page for OOB load_lds src
        zbuf[idx - 1966080] = 0;
    }
}

// ---------------------------------------------------------------------------
// LayerNorm: wave per row (180 f32 = 45 float4), writes bf16 [row][192] (pad 0)
// ---------------------------------------------------------------------------
__global__ __launch_bounds__(256)
void ln_k(const float* __restrict__ in, const float* __restrict__ w,
          const float* __restrict__ b, u16* __restrict__ out)
{
    int row = blockIdx.x * 4 + (threadIdx.x >> 6);
    int lane = threadIdx.x & 63;
    fvec4 v = {0.f, 0.f, 0.f, 0.f};
    if (lane < 45) v = *(const fvec4*)(in + (long)row * 180 + lane * 4);
    float s  = v.x + v.y + v.z + v.w;
    float sq = v.x * v.x + v.y * v.y + v.z * v.z + v.w * v.w;
    for (int m = 1; m < 64; m <<= 1) { s += __shfl_xor(s, m); sq += __shfl_xor(sq, m); }
    float mean = s * (1.f / 180.f);
    float var  = sq * (1.f / 180.f) - mean * mean;
    float rstd = rsqrtf(var + 1e-5f);
    if (lane < 45) {
        u16x4 o;
        #pragma unroll
        for (int j = 0; j < 4; j++) {
            int c = lane * 4 + j;
            o[j] = f2bf((v[j] - mean) * rstd * w[c] + b[c]);
        }
        *(u16x4*)(out + (long)row * 192 + lane * 4) = o;
    } else if (lane < 48) {
        u16x4 z = {0, 0, 0, 0};
        *(u16x4*)(out + (long)row * 192 + 180 + (lane - 45) * 4) = z;
    }
}

// ---------------------------------------------------------------------------
// GEMM: C[M][N] = A[M][K]bf16 @ Bt[N][K]bf16, 128x64 tile, 4 waves 2x2,
// 16x16x32 MFMA. Staging via global_load_lds w=16 (linear dest) with
// inverse-swizzled source; reads swizzled (kills stride-64B 8-way conflicts).
// EPI: 0=qkv scatter, 1=proj(+bias+resid f32), 2=fc1 gelu->bf16, 3=fc2
// ---------------------------------------------------------------------------
template<int KTOT, int EPI>
__global__ __launch_bounds__(256)
void gemm_k(const u16* __restrict__ A, const u16* __restrict__ Bt,
            const float* __restrict__ bias, const float* __restrict__ resid,
            void* __restrict__ o0, void* __restrict__ o1, void* __restrict__ o2)
{
    __shared__ u16 lds_a[128 * 32];
    __shared__ u16 lds_b[64 * 32];
    const int tid = threadIdx.x;
    const int l = tid & 63, wv = tid >> 6;
    const int wm = wv >> 1, wn = wv & 1;
    const int l15 = l & 15, lg = l >> 4;
    const int swz = (lg ^ ((l15 >> 1) & 3)) * 8;   // read-side XOR swizzle
    const long rowb = (long)blockIdx.x * 128;
    const int colb = blockIdx.y * 64;
    const f32x4 fz = {0.f, 0.f, 0.f, 0.f};

    f32x4 acc[4][2];
    #pragma unroll
    for (int i = 0; i < 4; i++) { acc[i][0] = fz; acc[i][1] = fz; }

    const int r = tid >> 2, g = tid & 3;
    const int gsw = (g ^ ((r >> 1) & 3)) * 8;      // source-side inverse swizzle
    char* dA0 = (char*)lds_a + wv * 1024;
    char* dA1 = (char*)lds_a + 4096 + wv * 1024;
    char* dB  = (char*)lds_b + wv * 1024;

    for (int kk = 0; kk < KTOT; kk += 32) {
        GLD16(A + (rowb + r) * KTOT + kk + gsw, dA0);
        GLD16(A + (rowb + 64 + r) * KTOT + kk + gsw, dA1);
        GLD16(Bt + (long)(colb + r) * KTOT + kk + gsw, dB);
        __syncthreads();
        bf16x8 af[4], bfr[2];
        #pragma unroll
        for (int mi = 0; mi < 4; mi++)
            af[mi] = *(const bf16x8*)(lds_a + (wm * 64 + mi * 16 + l15) * 32 + swz);
        #pragma unroll
        for (int nd = 0; nd < 2; nd++)
            bfr[nd] = *(const bf16x8*)(lds_b + (wn * 32 + nd * 16 + l15) * 32 + swz);
        #pragma unroll
        for (int mi = 0; mi < 4; mi++)
            #pragma unroll
            for (int nd = 0; nd < 2; nd++)
                acc[mi][nd] = __builtin_amdgcn_mfma_f32_16x16x32_bf16(af[mi], bfr[nd], acc[mi][nd], 0, 0, 0);
        __syncthreads();
    }

    #pragma unroll
    for (int mi = 0; mi < 4; mi++) {
        #pragma unroll
        for (int nd = 0; nd < 2; nd++) {
            #pragma unroll
            for (int rr = 0; rr < 4; rr++) {
                long t = rowb + wm * 64 + mi * 16 + lg * 4 + rr;
                int c = colb + wn * 32 + nd * 16 + l15;
                float v = acc[mi][nd][rr];
                if (EPI == 0) {
                    if (c < 540) {
                        v += bias[c];
                        int y = (int)(t >> 8), x = (int)(t & 255);
                        if (c < 180) {
                            int hh = c / 30, d = c % 30;
                            int win = ((y >> 4) << 4) | (x >> 4);
                            int qrow = ((y & 15) << 4) | (x & 15);
                            ((u16*)o0)[(((long)(win * 6 + hh)) * 256 + qrow) * 32 + d] = f2bf(v * SCALE_Q);
                        } else if (c < 360) {
                            int c2 = c - 180; int hh = c2 / 30, d = c2 % 30;
                            ((u16*)o1)[(t * 6 + hh) * 32 + d] = f2bf(v);
                        } else {
                            int c2 = c - 360; int hh = c2 / 30, d = c2 % 30;
                            ((u16*)o2)[(t * 6 + hh) * 32 + d] = f2bf(v);
                        }
                    }
                } else if (EPI == 1) {
                    if (c < 180) ((float*)o0)[t * 180 + c] = v + bias[c] + resid[t * 180 + c];
                } else if (EPI == 2) {
                    float bb = (c < 360) ? bias[c] : 0.f;
                    float xx = v + bb;
                    // tanh-form GELU: x * sigmoid(2*0.79788456*(x+0.044715x^3))
                    float u2n = -2.f * xx * (0.7978845608f + 0.0356774081f * xx * xx);
                    float ge = xx / (1.f + __expf(u2n));
                    ((u16*)o0)[t * 384 + c] = f2bf(ge);
                } else {
                    if (c < 180) ((float*)o0)[t * 180 + c] = v + bias[c] + resid[t * 180 + c];
                }
            }
        }
    }
}

// ---------------------------------------------------------------------------
// Attention: block=(window,head), 4 waves x 64 q-rows, 9 chunks of 64 keys.
// Swapped QK^T (S^T = K@Q^T). No online max (logits O(1); clamp 60 as guard;
// softmax shift-invariance makes this exact). Denominator via MFMA: V pad
// dim 30 staged as 1.0 for ALL keys (incl. out-of-image, matching jnp.pad
// softmax semantics) -> PV row 30 = sum(P). P round-trips per-wave LDS in
// two K=32 passes (b64 writes, no barrier). K staged via global_load_lds
// with XOR swizzle; OOB key lanes read a zeroed page.
// ---------------------------------------------------------------------------
__global__ __launch_bounds__(256, 4)
void attn_k(const u16* __restrict__ q_g, const u16* __restrict__ k_s,
            const u16* __restrict__ v_s, const u16* __restrict__ bias2,
            const u16* __restrict__ zbuf, u16* __restrict__ attn_out)
{
    __shared__ u16 kc[64 * 32];        // [key][dim32] (swizzled cols)
    __shared__ u16 vT[32 * 72];        // [dim][key64 pad72]
    __shared__ u16 ph[4][64 * 40];     // per wave: [q64][key32 pad40]

    const int w = blockIdx.x, h = blockIdx.y;
    const int wy = w >> 4, wx = w & 15;
    const int tid = threadIdx.x;
    const int wv = tid >> 6, l = tid & 63;
    const int l15 = l & 15, lg = l >> 4;
    const int swz = (lg ^ ((l15 >> 1) & 3)) * 8;
    const f32x4 fz = {0.f, 0.f, 0.f, 0.f};

    // Q B-fragments (col=q=l15, k=dims lg*8..+8); q pre-scaled by SCALE
    bf16x8 qb[4];
    #pragma unroll
    for (int ni = 0; ni < 4; ni++) {
        int qrow = wv * 64 + ni * 16 + l15;
        qb[ni] = *(const bf16x8*)(q_g + (((long)(w * 6 + h)) * 256 + qrow) * 32 + lg * 8);
    }

    f32x4 acc[2][4];   // [dim-frag][q-frag]
    #pragma unroll
    for (int i = 0; i < 2; i++)
        #pragma unroll
        for (int j = 0; j < 4; j++) acc[i][j] = fz;

    const int skey = tid >> 2, sg = tid & 3;
    const int ssw = (sg ^ ((skey >> 1) & 3)) * 8;  // inverse swizzle on source
    const int sd = tid & 31, skb = tid >> 5;
    char* kdst = (char*)kc + wv * 1024;

    for (int ch = 0; ch < 9; ++ch) {
        {   // stage K chunk [64][32] via global_load_lds; OOB -> zero page
            int n = ch * 64 + skey;
            int oy = n / 24, ox = n - oy * 24;
            int y = wy * 16 - 4 + oy, x = wx * 16 - 4 + ox;
            const u16* src = (y >= 0 && y < 256 && x >= 0 && x < 256)
                ? (k_s + (((long)(y * 256 + x)) * 6 + h) * 32 + ssw) : zbuf;
            GLD16(src, kdst);
        }
        {   // stage V chunk transposed [32][64]; dim 30 := 1.0 (sum row)
            u16x8 pv;
            #pragma unroll
            for (int j = 0; j < 8; j++) {
                int n = ch * 64 + skb * 8 + j;
                int oy = n / 24, ox = n - oy * 24;
                int y = wy * 16 - 4 + oy, x = wx * 16 - 4 + ox;
                pv[j] = (y >= 0 && y < 256 && x >= 0 && x < 256)
                      ? v_s[(((long)(y * 256 + x)) * 6 + h) * 32 + sd] : (u16)0;
                if (sd == 30) pv[j] = 0x3F80;  // bf16 1.0
            }
            *(u16x8*)(vT + sd * 72 + skb * 8) = pv;
        }
        __syncthreads();

        #pragma unroll
        for (int ks = 0; ks < 2; ks++) {
            #pragma unroll
            for (int mih = 0; mih < 2; mih++) {
                int mi = ks * 2 + mih;
                bf16x8 ka = *(const bf16x8*)(kc + (mi * 16 + l15) * 32 + swz);
                f32x4 s[4];
                #pragma unroll
                for (int ni = 0; ni < 4; ni++)
                    s[ni] = __builtin_amdgcn_mfma_f32_16x16x32_bf16(ka, qb[ni], fz, 0, 0, 0);
                #pragma unroll
                for (int ni = 0; ni < 4; ni++) {
                    u16x4 bb = *(const u16x4*)(bias2 +
                        (((long)h * 144 + ch * 16 + mi * 4 + lg) * 256 + wv * 64 + ni * 16 + l15) * 4);
                    u16x4 pp;
                    #pragma unroll
                    for (int rr = 0; rr < 4; rr++) {
                        float v = s[ni][rr] + bf2f(bb[rr]);
                        pp[rr] = f2bf(__expf(fminf(v, 60.f)));
                    }
                    *(u16x4*)(ph[wv] + (ni * 16 + l15) * 40 + mih * 16 + lg * 4) = pp;
                }
            }
            // O^T += V^T(ks slice) @ P^T
            bf16x8 va0 = *(const bf16x8*)(vT + l15 * 72 + ks * 32 + lg * 8);
            bf16x8 va1 = *(const bf16x8*)(vT + (16 + l15) * 72 + ks * 32 + lg * 8);
            #pragma unroll
            for (int ni = 0; ni < 4; ni++) {
                bf16x8 pb = *(const bf16x8*)(ph[wv] + (ni * 16 + l15) * 40 + lg * 8);
                acc[0][ni] = __builtin_amdgcn_mfma_f32_16x16x32_bf16(va0, pb, acc[0][ni], 0, 0, 0);
                acc[1][ni] = __builtin_amdgcn_mfma_f32_16x16x32_bf16(va1, pb, acc[1][ni], 0, 0, 0);
            }
        }
        __syncthreads();
    }

    // epilogue: row 30 of O^T is sum(P); divide and scatter dims<30
    #pragma unroll
    for (int ni = 0; ni < 4; ni++) {
        float sum = __shfl(acc[1][ni][2], 48 + l15);   // dim30 lives at lg=3,rr=2
        float inv = 1.f / sum;
        int q = wv * 64 + ni * 16 + l15;
        int y = wy * 16 + (q >> 4), x = wx * 16 + (q & 15);
        long base = ((long)(y * 256 + x)) * 192 + h * 30;
        #pragma unroll
        for (int mi2 = 0; mi2 < 2; mi2++)
            #pragma unroll
            for (int rr = 0; rr < 4; rr++) {
                int dim = mi2 * 16 + lg * 4 + rr;
                if (dim < 30)
                    attn_out[base + dim] = f2bf(acc[mi2][ni][rr] * inv);
            }
    }
}

// ---------------------------------------------------------------------------
extern "C" void kernel_launch(void* const* d_in, const int* in_sizes, int n_in,
                              void* d_out, int out_size, void* d_ws, size_t ws_size,
                              hipStream_t stream)
{
    (void)in_sizes; (void)n_in; (void)out_size; (void)ws_size;
    const float* x      = (const float*)d_in[0];
    const int*   rpi    = (const int*)d_in[1];
    const float* n1w    = (const float*)d_in[2];
    const float* n1b    = (const float*)d_in[3];
    const float* qkv_w  = (const float*)d_in[4];
    const float* qkv_b  = (const float*)d_in[5];
    const float* rpb    = (const float*)d_in[6];
    const float* proj_w = (const float*)d_in[7];
    const float* proj_b = (const float*)d_in[8];
    const float* n2w    = (const float*)d_in[9];
    const float* n2b    = (const float*)d_in[10];
    const float* fc1_w  = (const float*)d_in[11];
    const float* fc1_b  = (const float*)d_in[12];
    const float* fc2_w  = (const float*)d_in[13];
    const float* fc2_b  = (const float*)d_in[14];
    float* out = (float*)d_out;

    char* ws = (char*)d_ws;
    size_t off = 0;
    auto alloc = [&](size_t bytes) -> void* {
        void* p = ws + off; off += (bytes + 511) & ~(size_t)511; return p;
    };
    u16*   xn     = (u16*)alloc(65536ull * 192 * 2);  // ln1 out, reused for ln2 out
    u16*   q_g    = (u16*)alloc(65536ull * 192 * 2);  // [win][h][qrow][32]
    u16*   k_s    = (u16*)alloc(65536ull * 192 * 2);  // [y][x][h][32]
    u16*   v_s    = (u16*)alloc(65536ull * 192 * 2);
    u16*   ao     = (u16*)alloc(65536ull * 192 * 2);  // attn out bf16 [t][192]
    float* x2     = (float*)alloc(65536ull * 180 * 4);
    u16*   bias2  = (u16*)alloc(6ull * 576 * 256 * 2);
    u16*   qkvT   = (u16*)alloc(576ull * 192 * 2);
    u16*   projT  = (u16*)alloc(192ull * 192 * 2);
    u16*   fc1T   = (u16*)alloc(384ull * 192 * 2);
    u16*   fc2T   = (u16*)alloc(192ull * 384 * 2);
    u16*   zbuf   = (u16*)alloc(256);
    u16*   h1     = q_g;  // q_g+k_s adjacent = 65536*384*2 bytes for fc1 out

    prep_k<<<dim3(7681), dim3(256), 0, stream>>>(qkv_w, proj_w, fc1_w, fc2_w,
        rpi, rpb, qkvT, projT, fc1T, fc2T, bias2, (unsigned*)k_s, (unsigned*)ao, zbuf);
    ln_k<<<dim3(16384), dim3(256), 0, stream>>>(x, n1w, n1b, xn);
    gemm_k<192, 0><<<dim3(512, 9), dim3(256), 0, stream>>>(
        xn, qkvT, qkv_b, (const float*)nullptr, q_g, k_s, v_s);
    attn_k<<<dim3(256, 6), dim3(256), 0, stream>>>(q_g, k_s, v_s, bias2, zbuf, ao);
    gemm_k<192, 1><<<dim3(512, 3), dim3(256), 0, stream>>>(
        ao, projT, proj_b, x, x2, nullptr, nullptr);
    ln_k<<<dim3(16384), dim3(256), 0, stream>>>(x2, n2w, n2b, xn);
    gemm_k<192, 2><<<dim3(512, 6), dim3(256), 0, stream>>>(
        xn, fc1T, fc1_b, (const float*)nullptr, h1, nullptr, nullptr);
    gemm_k<384, 3><<<dim3(512, 3), dim3(256), 0, stream>>>(
        h1, fc2T, fc2_b, x2, out, nullptr, nullptr);
}